// Round 4
// 628.753 us; speedup vs baseline: 1.2769x; 1.2769x over previous
//
#include <hip/hip_runtime.h>

#define B_ 32
#define T_ 12
#define N_ 300
#define D_ 128
#define M_ 288

#define DELTA 2.5e-3f   // >= 2x hard bound on |bf16-stored split score - exact fp32 score|

typedef float f32x4 __attribute__((ext_vector_type(4)));
typedef short s16x8 __attribute__((ext_vector_type(8)));

// ws byte layout (286720 B total)
#define WS_WQT_B    0            // fp32 wq^T [128][128]            65536 B
#define WS_KF32_B   65536        // fp32 k, row-major [288][128]   147456 B
#define WS_VTB_B    212992       // bf16 v^T [128][288]             73728 B

static __device__ __forceinline__ unsigned short f2bf(float f) {
  unsigned int u = __float_as_uint(f);
  u += 0x7FFFu + ((u >> 16) & 1u);          // RNE
  return (unsigned short)(u >> 16);
}
static __device__ __forceinline__ float bf2f(unsigned short h) {
  return __uint_as_float(((unsigned int)h) << 16);
}
// LDS swizzles (XOR row bits into 16B-slot bits -> conflict-free frag reads)
static __device__ __forceinline__ int qb_byte(int row, int bb) {  // row stride 256B
  return row * 256 + (bb ^ ((row & 7) << 4));
}
static __device__ __forceinline__ int sb_byte(int row, int bb) {  // row stride 576B
  return row * 576 + (bb ^ ((row & 3) << 4));
}
// split 8 fp32 -> bf16 hi + bf16 lo fragments
static __device__ __forceinline__ void split8(const float4 fa, const float4 fb,
                                              s16x8* hi, s16x8* lo) {
  float f[8] = {fa.x, fa.y, fa.z, fa.w, fb.x, fb.y, fb.z, fb.w};
#pragma unroll
  for (int i = 0; i < 8; ++i) {
    const unsigned short h = f2bf(f[i]);
    (*hi)[i] = (short)h;
    (*lo)[i] = (short)f2bf(f[i] - bf2f(h));
  }
}

// ---------------------------------------------------------------------------
// prep: k (fp32, round-0-exact accumulation order), v^T (bf16), wq^T (fp32).
// blocks 0..287: one memory row (128 thr: k, 128 thr: v). blocks 288..351: wq cols.
// ---------------------------------------------------------------------------
__global__ __launch_bounds__(256) void prep_kernel(
    const float* __restrict__ memory,
    const float* __restrict__ wk, const float* __restrict__ bk,
    const float* __restrict__ wv, const float* __restrict__ bv,
    const float* __restrict__ wq,
    float* __restrict__ ws) {
  __shared__ float mrow[D_];
  float* wqT  = (float*)((char*)ws + WS_WQT_B);
  float* kf32 = (float*)((char*)ws + WS_KF32_B);
  unsigned short* vTb = (unsigned short*)((char*)ws + WS_VTB_B);
  const int blk = blockIdx.x, tid = threadIdx.x;
  if (blk < M_) {
    if (tid < D_) mrow[tid] = memory[blk * D_ + tid];
    __syncthreads();
    const int d = tid & 127;
    const float* w = (tid >> 7) ? wv : wk;
    // single accumulator, ascending e, bias last — bit-exact vs round-0 prep
    float a = 0.f;
    for (int e8 = 0; e8 < D_; e8 += 8) {
      const float4 wa = *(const float4*)&w[d * D_ + e8];
      const float4 wb = *(const float4*)&w[d * D_ + e8 + 4];
      const float4 ma = *(const float4*)&mrow[e8];
      const float4 mb = *(const float4*)&mrow[e8 + 4];
      a += wa.x * ma.x; a += wa.y * ma.y; a += wa.z * ma.z; a += wa.w * ma.w;
      a += wb.x * mb.x; a += wb.y * mb.y; a += wb.z * mb.z; a += wb.w * mb.w;
    }
    if (tid >> 7) {
      vTb[d * M_ + blk] = f2bf(a + bv[d]);
    } else {
      kf32[blk * D_ + d] = a + bk[d];
    }
  } else {
    const int e = (blk - M_) * 2 + (tid >> 7);
    const int d = tid & 127;
    wqT[e * D_ + d] = wq[d * D_ + e];
  }
}

// ---------------------------------------------------------------------------
// main: one block per (b,n). 256 threads (4 waves). Split-bf16 MFMA scores,
// certified candidates, round-0-bit-exact fp32 re-rank, MFMA PV.
// ---------------------------------------------------------------------------
__global__ __launch_bounds__(256) void attn_kernel(
    const float* __restrict__ x,
    const float* __restrict__ memory,
    const float* __restrict__ bq,
    const float* __restrict__ ws,
    float* __restrict__ out) {
  const float* wqT  = (const float*)((const char*)ws + WS_WQT_B);
  const float* kf32 = (const float*)((const char*)ws + WS_KF32_B);
  const unsigned short* vTb = (const unsigned short*)((const char*)ws + WS_VTB_B);

  __shared__ __align__(16) float xs[T_ * D_];             // 6144 B
  __shared__ __align__(16) float qf[T_ * D_];             // 6144 B (fp32 q, re-rank)
  __shared__ __align__(16) unsigned short qhb[16 * D_];   // 4096 B (bf16 q-hi, swizzled)
  __shared__ __align__(16) unsigned short qlb[16 * D_];   // 4096 B (bf16 q-lo, swizzled)
  __shared__ __align__(16) unsigned short Sb[16 * M_];    // 9216 B (scores -> P, swizzled)
  __shared__ float rowinv[T_];
  __shared__ int   top2i[T_ * 2];
  __shared__ int   cand[T_][32];

  const int tid = threadIdx.x;
  const int bid = blockIdx.x;
  const int b = bid / N_;
  const int n = bid % N_;
  const int lane = tid & 63, wave = tid >> 6;
  const size_t sec4 = (size_t)B_ * T_ * N_ * (D_ / 4);

  // ---- phase 1: x -> LDS, and write-through to out section 1 -------------
  for (int i = tid; i < T_ * (D_ / 4); i += 256) {
    const int t = i >> 5, d4 = i & 31;
    const size_t g = (((size_t)b * T_ + t) * N_ + n) * (D_ / 4) + d4;
    const float4 v4 = ((const float4*)x)[g];
    ((float4*)xs)[i] = v4;
    ((float4*)out)[sec4 + g] = v4;      // x passthrough (replaces memcpy)
  }
  {  // zero q pad rows 12..15 (both hi and lo)
    ((unsigned int*)((char*)qhb + 12 * 256))[tid] = 0u;
    ((unsigned int*)((char*)qlb + 12 * 256))[tid] = 0u;
  }
  __syncthreads();

  // ---- phase 2: q = x @ wq^T + bq (fp32); store fp32 + bf16 hi/lo split --
  {
    const int d = tid & 127, h = tid >> 7;
    float acc[6] = {0.f, 0.f, 0.f, 0.f, 0.f, 0.f};
    for (int e4 = 0; e4 < D_ / 4; ++e4) {
      const int e = e4 * 4;
      const float w0 = wqT[(e + 0) * D_ + d];
      const float w1 = wqT[(e + 1) * D_ + d];
      const float w2 = wqT[(e + 2) * D_ + d];
      const float w3 = wqT[(e + 3) * D_ + d];
#pragma unroll
      for (int j = 0; j < 6; ++j) {
        const float4 xv = *(const float4*)&xs[(h * 6 + j) * D_ + e];
        acc[j] += xv.x * w0; acc[j] += xv.y * w1;
        acc[j] += xv.z * w2; acc[j] += xv.w * w3;
      }
    }
    const float bqd = bq[d];
#pragma unroll
    for (int j = 0; j < 6; ++j) {
      const int t = h * 6 + j;
      const float qv = acc[j] + bqd;
      qf[t * D_ + d] = qv;
      const unsigned short qh = f2bf(qv);
      *(unsigned short*)((char*)qhb + qb_byte(t, 2 * d)) = qh;
      *(unsigned short*)((char*)qlb + qb_byte(t, 2 * d)) = f2bf(qv - bf2f(qh));
    }
  }
  __syncthreads();

  // ---- phase 3: scores = (qh+ql)(kh+kl) via 4x MFMA; k split in-register -
  {
    const int arow = lane & 15;
    const int agrp = (lane >> 4) * 16;   // byte offset of this lane's 8-elem group
    const int ke0  = (lane >> 4) * 8;    // elem offset within k row chunk
    s16x8 ah[4], al[4];
#pragma unroll
    for (int kt = 0; kt < 4; ++kt) {
      ah[kt] = *(const s16x8*)((const char*)qhb + qb_byte(arow, kt * 64 + agrp));
      al[kt] = *(const s16x8*)((const char*)qlb + qb_byte(arow, kt * 64 + agrp));
    }
    for (int ct = wave; ct < 18; ct += 4) {
      const int m = ct * 16 + arow;
      const float* krow = kf32 + m * D_;
      float4 raw[8];
#pragma unroll
      for (int kt = 0; kt < 4; ++kt) {
        raw[2 * kt]     = *(const float4*)&krow[kt * 32 + ke0];
        raw[2 * kt + 1] = *(const float4*)&krow[kt * 32 + ke0 + 4];
      }
      f32x4 acc = {0.f, 0.f, 0.f, 0.f};
#pragma unroll
      for (int kt = 0; kt < 4; ++kt) {
        s16x8 bh, bl;
        split8(raw[2 * kt], raw[2 * kt + 1], &bh, &bl);
        acc = __builtin_amdgcn_mfma_f32_16x16x32_bf16(ah[kt], bh, acc, 0, 0, 0);
        acc = __builtin_amdgcn_mfma_f32_16x16x32_bf16(al[kt], bh, acc, 0, 0, 0);
        acc = __builtin_amdgcn_mfma_f32_16x16x32_bf16(ah[kt], bl, acc, 0, 0, 0);
        acc = __builtin_amdgcn_mfma_f32_16x16x32_bf16(al[kt], bl, acc, 0, 0, 0);
      }
#pragma unroll
      for (int j = 0; j < 4; ++j) {   // C/D: col=lane&15, row=(lane>>4)*4+j
        const int row = (lane >> 4) * 4 + j;
        *(unsigned short*)((char*)Sb + sb_byte(row, 2 * m)) =
            f2bf(acc[j] * 0.08838834764831845f);   // 1/sqrt(128)
      }
    }
  }
  __syncthreads();

  // ---- phase 4: softmax + certified candidates + round-0-exact top-2 -----
  {
    for (int r = wave; r < T_; r += 4) {
      float sv[5];
#pragma unroll
      for (int p = 0; p < 5; ++p) {
        const int m = lane + p * 64;
        sv[p] = (m < M_)
            ? bf2f(*(const unsigned short*)((const char*)Sb + sb_byte(r, 2 * m)))
            : -__builtin_inff();
      }
      // values-only top-2 across the row (bf16-path values)
      float v1 = -__builtin_inff(), v2 = -__builtin_inff();
#pragma unroll
      for (int p = 0; p < 5; ++p) {
        const float s = sv[p];
        if (s > v1)      { v2 = v1; v1 = s; }
        else if (s > v2) { v2 = s; }
      }
#pragma unroll
      for (int off = 32; off > 0; off >>= 1) {
        const float o1 = __shfl_xor(v1, off, 64);
        const float o2 = __shfl_xor(v2, off, 64);
        if (o1 > v1) { v2 = fmaxf(v1, o2); v1 = o1; }
        else         { v2 = fmaxf(v2, o1); }
      }
      // candidates: all m with stored score >= v2 - DELTA (ballot, ascending m)
      const float thr = v2 - DELTA;
      int cnt = 0;
#pragma unroll
      for (int p = 0; p < 5; ++p) {
        const int m = lane + p * 64;
        const bool c = (m < M_) && (sv[p] >= thr);
        const unsigned long long mask = __ballot(c);
        if (c) {
          const int pos = cnt + __popcll(mask & ((1ull << lane) - 1ull));
          if (pos < 32) cand[r][pos] = m;
        }
        cnt += (int)__popcll(mask);
      }
      if (cnt > 32) cnt = 32;
      // softmax (rowmax = v1)
      float psum = 0.f;
#pragma unroll
      for (int p = 0; p < 5; ++p) {
        const int m = lane + p * 64;
        if (m < M_) {
          const float e = expf(sv[p] - v1);
          *(unsigned short*)((char*)Sb + sb_byte(r, 2 * m)) = f2bf(e);  // P in place
          psum += e;
        }
      }
#pragma unroll
      for (int off = 32; off > 0; off >>= 1) psum += __shfl_xor(psum, off, 64);

      // re-rank: lane c computes candidate c's dot SEQUENTIALLY in ascending e
      // (bit-exact replica of the round-0 score arithmetic), scaled compare.
      float V1, V2 = -__builtin_inff();
      int I1, I2 = 0x7FFFFFFF;
      {
        float mv = -__builtin_inff(); int mi = 0x7FFFFFFF;
        if (lane < cnt) {
          const int m = cand[r][lane];
          const float* kr = kf32 + m * D_;
          const float* qr = qf + r * D_;
          float acc = 0.f;
          for (int e4 = 0; e4 < D_ / 4; ++e4) {
            const float4 qv = *(const float4*)&qr[e4 * 4];
            const float4 kv = *(const float4*)&kr[e4 * 4];
            acc += qv.x * kv.x; acc += qv.y * kv.y;
            acc += qv.z * kv.z; acc += qv.w * kv.w;
          }
          mv = acc * 0.08838834764831845f;
          mi = m;
        }
        V1 = mv; I1 = mi;
#pragma unroll
        for (int off = 32; off > 0; off >>= 1) {
          const float o1 = __shfl_xor(V1, off, 64);
          const int  oi1 = __shfl_xor(I1, off, 64);
          const float o2 = __shfl_xor(V2, off, 64);
          const int  oi2 = __shfl_xor(I2, off, 64);
          const bool b_first = (o1 > V1) || (o1 == V1 && oi1 < I1);
          if (b_first) {
            const bool a_second = (V1 > o2) || (V1 == o2 && I1 < oi2);
            V2 = a_second ? V1 : o2;  I2 = a_second ? I1 : oi2;
            V1 = o1; I1 = oi1;
          } else {
            const bool b_second = (o1 > V2) || (o1 == V2 && oi1 < I2);
            if (b_second) { V2 = o1; I2 = oi1; }
          }
        }
      }
      if (lane == 0) {
        rowinv[r]        = 1.0f / psum;
        top2i[r * 2]     = I1;
        top2i[r * 2 + 1] = I2;
      }
    }
  }
  __syncthreads();

  // ---- phase 5: out = (P @ v) * rowinv via MFMA --------------------------
  {
    const int prow = lane & 15;
    const int d0 = wave * 32 + prow;
    const int d1 = d0 + 16;
    f32x4 acc0 = {0.f, 0.f, 0.f, 0.f}, acc1 = {0.f, 0.f, 0.f, 0.f};
#pragma unroll
    for (int kt = 0; kt < 9; ++kt) {
      const int mb2 = kt * 64 + ((lane >> 4) * 16);
      const s16x8 pf = *(const s16x8*)((const char*)Sb + sb_byte(prow, mb2));
      const s16x8 b0 = *(const s16x8*)((const char*)vTb + d0 * 576 + mb2);
      const s16x8 b1 = *(const s16x8*)((const char*)vTb + d1 * 576 + mb2);
      acc0 = __builtin_amdgcn_mfma_f32_16x16x32_bf16(pf, b0, acc0, 0, 0, 0);
      acc1 = __builtin_amdgcn_mfma_f32_16x16x32_bf16(pf, b1, acc1, 0, 0, 0);
    }
#pragma unroll
    for (int j = 0; j < 4; ++j) {
      const int r = (lane >> 4) * 4 + j;
      if (r < T_) {
        const float sc = rowinv[r];
        const size_t o = (((size_t)b * T_ + r) * N_ + n) * D_;
        out[o + d0] = acc0[j] * sc;
        out[o + d1] = acc1[j] * sc;
      }
    }
  }

  // ---- phase 6: pos/neg gathers (float4 passthrough, exact) --------------
  {
    for (int i = tid; i < 2 * T_ * (D_ / 4); i += 256) {
      const int sel = i / (T_ * (D_ / 4));
      const int r   = (i >> 5) % T_;
      const int d4  = i & 31;
      const int idx = top2i[r * 2 + sel];
      ((float4*)out)[(2 + sel) * sec4 + (((size_t)b * T_ + r) * N_ + n) * (D_ / 4) + d4] =
          ((const float4*)memory)[idx * (D_ / 4) + d4];
    }
  }
}

// ---------------------------------------------------------------------------
extern "C" void kernel_launch(void* const* d_in, const int* in_sizes, int n_in,
                              void* d_out, int out_size, void* d_ws, size_t ws_size,
                              hipStream_t stream) {
  const float* x      = (const float*)d_in[0];
  const float* memory = (const float*)d_in[1];
  const float* wq     = (const float*)d_in[2];
  const float* bq     = (const float*)d_in[3];
  const float* wk     = (const float*)d_in[4];
  const float* bk     = (const float*)d_in[5];
  const float* wv     = (const float*)d_in[6];
  const float* bv     = (const float*)d_in[7];
  float* out = (float*)d_out;
  float* ws  = (float*)d_ws;

  prep_kernel<<<dim3(M_ + D_ / 2), dim3(256), 0, stream>>>(memory, wk, bk, wv, bv, wq, ws);
  attn_kernel<<<dim3(B_ * N_), dim3(256), 0, stream>>>(x, memory, bq, ws, out);
}